// Round 1
// baseline (293.101 us; speedup 1.0000x reference)
//
#include <hip/hip_runtime.h>
#include <hip/hip_bf16.h>
#include <stdint.h>

// ---------------------------------------------------------------------------
// TripletAggregateUngated: B=2, N=256, W=128, H=8, D=16
// Pipeline:
//  K0: weight prep (bf16 transposed/permuted copies of W_V|W_E, W_O)
//  K1: LayerNorm + [e_ln @ (W_V|W_E)] MFMA GEMM; scatter V into einsum layouts
//  K2: softmax over k for A_in (axis=2) and A_out (axis=1, transposed store)
//  K3: Va_in/Va_out einsums as batched GEMMs (per b,h,part), 128x128 tiles
//  K4: Va @ W_O + b_O final GEMM
// All heavy GEMMs: v_mfma_f32_16x16x32_bf16, global_load_lds(16B) staging with
// XOR chunk swizzle (16B chunks) for conflict-free ds_read_b128 fragments.
// ---------------------------------------------------------------------------

typedef short short8 __attribute__((ext_vector_type(8)));
typedef float floatx4 __attribute__((ext_vector_type(4)));

#define AS1(p) ((const __attribute__((address_space(1))) void*)(p))
#define AS3(p) ((__attribute__((address_space(3))) void*)(p))

__device__ inline short f2bf(float v) {
    __hip_bfloat16 h = __float2bfloat16(v);
    short s;
    __builtin_memcpy(&s, &h, 2);
    return s;
}

// ---------------------------------------------------------------------------
// K0: weight prep.
// Wcat[n][k] (n<256: W_V[k][n]; n>=256: W_E[k][n-256]) as bf16, k contiguous.
// WOt[w][c'] = W_O[(c'&15)*16 + (c'>>4)][w]  (c' = hh*16+d permutation), bf16.
// ---------------------------------------------------------------------------
__global__ __launch_bounds__(128) void k0_prep(const float* __restrict__ WV,
                                               const float* __restrict__ WE,
                                               const float* __restrict__ WO,
                                               short* __restrict__ Wcat,
                                               short* __restrict__ WOt) {
    int bx = blockIdx.x;
    if (bx < 272) {
        int n = bx, k = threadIdx.x;  // 128 threads
        float v = (n < 256) ? WV[k * 256 + n] : WE[k * 16 + (n - 256)];
        Wcat[n * 128 + k] = f2bf(v);
    } else {
        int w = bx - 272;
        for (int it = 0; it < 2; ++it) {
            int c = threadIdx.x + it * 128;
            float v = WO[((c & 15) * 16 + (c >> 4)) * 128 + w];
            WOt[w * 256 + c] = f2bf(v);
        }
    }
}

// ---------------------------------------------------------------------------
// K1: per 8x8 edge patch (64 edges): LN -> bf16 A-tile, GEMM vs Wcat (272 cols),
// epilogue: E cols -> Ef (f32, direct); V cols -> LDS -> scattered 16B runs:
//   VinT [b][h][j=r1][d][k=r2]   VoutT [b][h][j=r2][d][k=r1]
// ---------------------------------------------------------------------------
__global__ __launch_bounds__(256) void k1_ln_proj(
    const float* __restrict__ e, const float* __restrict__ ln_g,
    const float* __restrict__ ln_b, const float* __restrict__ b_V,
    const float* __restrict__ b_E, const short* __restrict__ Wcat,
    short* __restrict__ VinT, short* __restrict__ VoutT,
    float* __restrict__ Ef) {
    __shared__ short As[64][136];        // padded: conflict-free b128 frag reads
    __shared__ short Wc[272 * 16 * 8];   // swizzled 16B chunks (69632 B)
    __shared__ short Cs[64][288];        // V outputs staging for scatter

    const int tid = threadIdx.x;
    const int lane = tid & 63;
    const int w = tid >> 6;
    const int bx = blockIdx.x;
    const int b = bx >> 10;
    const int rem = bx & 1023;
    const int r1_0 = (rem >> 5) << 3;
    const int r2_0 = (rem & 31) << 3;

    // async stage Wcat -> Wc (272 rows x 16 chunks, XOR-swizzled within row)
    for (int it = 0; it < 17; ++it) {
        int c0 = (w * 17 + it) * 64;     // wave-uniform chunk base
        int lc = c0 + lane;
        int n = lc >> 4;
        int ck = (lc & 15) ^ (n & 15);
        __builtin_amdgcn_global_load_lds(AS1(Wcat + n * 128 + ck * 8),
                                         AS3(&Wc[c0 * 8]), 16, 0, 0);
    }

    // LayerNorm: 4 threads per edge row, 32 f32 each
    {
        int row = tid >> 2, seg = tid & 3;
        int r1l = row >> 3, r2l = row & 7;
        const float* ep = e + (((size_t)b * 256 + (r1_0 + r1l)) * 256 +
                               (r2_0 + r2l)) * 128 + seg * 32;
        float v[32];
        float s = 0.f, s2 = 0.f;
#pragma unroll
        for (int i = 0; i < 8; ++i) {
            float4 t = ((const float4*)ep)[i];
            v[4 * i] = t.x; v[4 * i + 1] = t.y; v[4 * i + 2] = t.z; v[4 * i + 3] = t.w;
            s += t.x + t.y + t.z + t.w;
            s2 += t.x * t.x + t.y * t.y + t.z * t.z + t.w * t.w;
        }
        s += __shfl_xor(s, 1); s2 += __shfl_xor(s2, 1);
        s += __shfl_xor(s, 2); s2 += __shfl_xor(s2, 2);
        float mean = s * 0.0078125f;
        float var = s2 * 0.0078125f - mean * mean;
        float rs = rsqrtf(var + 1e-5f);
#pragma unroll
        for (int i = 0; i < 8; ++i) {
            float4 gg = ((const float4*)(ln_g + seg * 32))[i];
            float4 bb = ((const float4*)(ln_b + seg * 32))[i];
            As[row][seg * 32 + 4 * i + 0] = f2bf((v[4 * i + 0] - mean) * rs * gg.x + bb.x);
            As[row][seg * 32 + 4 * i + 1] = f2bf((v[4 * i + 1] - mean) * rs * gg.y + bb.y);
            As[row][seg * 32 + 4 * i + 2] = f2bf((v[4 * i + 2] - mean) * rs * gg.z + bb.z);
            As[row][seg * 32 + 4 * i + 3] = f2bf((v[4 * i + 3] - mean) * rs * gg.w + bb.w);
        }
    }
    __syncthreads();

    // GEMM: wave w owns 16 edge rows; 17 n-subtiles; K=128 (4 mfma steps)
    const int ln_ = lane & 15, quad = lane >> 4;
    const int m0 = w * 16;
    short8 af[4];
#pragma unroll
    for (int kk = 0; kk < 4; ++kk)
        af[kk] = *(const short8*)&As[m0 + ln_][kk * 32 + quad * 8];
    floatx4 acc[17] = {};
#pragma unroll
    for (int kk = 0; kk < 4; ++kk) {
        int ck = kk * 4 + quad;
#pragma unroll
        for (int nt = 0; nt < 17; ++nt) {
            int n = nt * 16 + ln_;
            short8 bq = *(const short8*)&Wc[(n * 16 + (ck ^ (n & 15))) * 8];
            acc[nt] = __builtin_amdgcn_mfma_f32_16x16x32_bf16(af[kk], bq, acc[nt], 0, 0, 0);
        }
    }
    // epilogue: bias, V->Cs (bf16), E->global f32
#pragma unroll
    for (int nt = 0; nt < 17; ++nt) {
        int c = nt * 16 + ln_;
        float bias = (nt < 16) ? b_V[c] : b_E[c - 256];
#pragma unroll
        for (int r = 0; r < 4; ++r) {
            int edge = m0 + quad * 4 + r;
            float val = acc[nt][r] + bias;
            if (nt < 16) {
                Cs[edge][c] = f2bf(val);
            } else {
                Ef[(((size_t)b * 256 + (r1_0 + (edge >> 3))) * 256 +
                    (r2_0 + (edge & 7))) * 16 + (c - 256)] = val;
            }
        }
    }
    __syncthreads();

    // scatter: 2048 16-B runs. t -> (part, h, d), loop over rl.
    {
        int part = tid >> 7;
        int hh = (tid >> 4) & 7;
        int d = tid & 15;
#pragma unroll
        for (int rl = 0; rl < 8; ++rl) {
            short8 vals;
            if (part == 0) {
#pragma unroll
                for (int q = 0; q < 8; ++q) vals[q] = Cs[rl * 8 + q][d * 8 + hh];
                size_t off = ((((size_t)b * 8 + hh) * 256 + (r1_0 + rl)) * 16 + d) * 256 + r2_0;
                *(short8*)(VinT + off) = vals;
            } else {
#pragma unroll
                for (int q = 0; q < 8; ++q) vals[q] = Cs[q * 8 + rl][128 + d * 8 + hh];
                size_t off = ((((size_t)b * 8 + hh) * 256 + (r2_0 + rl)) * 16 + d) * 256 + r1_0;
                *(short8*)(VoutT + off) = vals;
            }
        }
    }
}

// ---------------------------------------------------------------------------
// K2: softmaxes. Block = (b,i). A_in over k of Ef[b][i][k][h]; A_out over k of
// Ef[b][k][i][8+h]. Outputs bf16 [b][h][i][k].
// ---------------------------------------------------------------------------
__global__ __launch_bounds__(256) void k2_softmax(const float* __restrict__ Ef,
                                                  const float* __restrict__ mask,
                                                  short* __restrict__ Ain,
                                                  short* __restrict__ AoutT) {
    __shared__ float red[4][16];
    int bi = blockIdx.x;
    int b = bi >> 8, i = bi & 255;
    int k = threadIdx.x;
    int wid = k >> 6, lane = k & 63;

    float v[16];
    {
        const float4* pin = (const float4*)(Ef + (((size_t)b * 256 + i) * 256 + k) * 16);
        float4 a0 = pin[0], a1 = pin[1];
        float mi = mask[((size_t)b * 256 + i) * 256 + k];
        v[0] = a0.x + mi; v[1] = a0.y + mi; v[2] = a0.z + mi; v[3] = a0.w + mi;
        v[4] = a1.x + mi; v[5] = a1.y + mi; v[6] = a1.z + mi; v[7] = a1.w + mi;
        const float4* po = (const float4*)(Ef + (((size_t)b * 256 + k) * 256 + i) * 16 + 8);
        float4 c0 = po[0], c1 = po[1];
        float mo = mask[((size_t)b * 256 + k) * 256 + i];
        v[8] = c0.x + mo; v[9] = c0.y + mo; v[10] = c0.z + mo; v[11] = c0.w + mo;
        v[12] = c1.x + mo; v[13] = c1.y + mo; v[14] = c1.z + mo; v[15] = c1.w + mo;
    }
    // block max per channel
    float wm[16];
#pragma unroll
    for (int ch = 0; ch < 16; ++ch) {
        float m = v[ch];
#pragma unroll
        for (int off = 1; off < 64; off <<= 1) m = fmaxf(m, __shfl_xor(m, off));
        wm[ch] = m;
    }
    if (lane == 0) {
#pragma unroll
        for (int ch = 0; ch < 16; ++ch) red[wid][ch] = wm[ch];
    }
    __syncthreads();
    float bmax[16];
#pragma unroll
    for (int ch = 0; ch < 16; ++ch)
        bmax[ch] = fmaxf(fmaxf(red[0][ch], red[1][ch]), fmaxf(red[2][ch], red[3][ch]));
    __syncthreads();
    // exp + block sum
    float p[16], ws[16];
#pragma unroll
    for (int ch = 0; ch < 16; ++ch) {
        p[ch] = __expf(v[ch] - bmax[ch]);
        float s = p[ch];
#pragma unroll
        for (int off = 1; off < 64; off <<= 1) s += __shfl_xor(s, off);
        ws[ch] = s;
    }
    if (lane == 0) {
#pragma unroll
        for (int ch = 0; ch < 16; ++ch) red[wid][ch] = ws[ch];
    }
    __syncthreads();
#pragma unroll
    for (int ch = 0; ch < 8; ++ch) {
        float inv = 1.f / (red[0][ch] + red[1][ch] + red[2][ch] + red[3][ch]);
        Ain[(((size_t)b * 8 + ch) * 256 + i) * 256 + k] = f2bf(p[ch] * inv);
    }
#pragma unroll
    for (int ch = 8; ch < 16; ++ch) {
        float inv = 1.f / (red[0][ch] + red[1][ch] + red[2][ch] + red[3][ch]);
        AoutT[(((size_t)b * 8 + (ch - 8)) * 256 + i) * 256 + k] = f2bf(p[ch] * inv);
    }
}

// ---------------------------------------------------------------------------
// K3: per (b,h,part): C[i, jd] = sum_k A'[i,k] * V'[jd,k]. 128x128 tiles,
// K=256 fully staged (A 64KB + B 64KB LDS). Writes Va_p[b][i][j][hh*16+d] bf16.
// ---------------------------------------------------------------------------
__global__ __launch_bounds__(256) void k3_einsum(const short* __restrict__ Ain,
                                                 const short* __restrict__ AoutT,
                                                 const short* __restrict__ VinT,
                                                 const short* __restrict__ VoutT,
                                                 short* __restrict__ VaP) {
    __shared__ short AB[8192 * 8];  // 128 KB: A chunks [0,4096), B chunks [4096,8192)
    const int tid = threadIdx.x, lane = tid & 63, w = tid >> 6;
    const int jd0 = blockIdx.x * 128;
    const int i0 = blockIdx.y * 128;
    const int z = blockIdx.z;
    const int b = z >> 4, part = (z >> 3) & 1, h = z & 7;

    const short* Abase = (part ? AoutT : Ain) + ((size_t)(b * 8 + h)) * 65536 + (size_t)i0 * 256;
    const short* Bbase = (part ? VoutT : VinT) + ((size_t)(b * 8 + h)) * 1048576 + (size_t)jd0 * 256;

    for (int it = 0; it < 32; ++it) {
        int c0 = (w * 32 + it) * 64;
        int lc = c0 + lane;
        const short* g;
        if (c0 < 4096) {
            int r = lc >> 5;
            int ck = (lc & 31) ^ (r & 31);
            g = Abase + r * 256 + ck * 8;
        } else {
            int lb = lc - 4096;
            int r = lb >> 5;
            int ck = (lb & 31) ^ (r & 31);
            g = Bbase + r * 256 + ck * 8;
        }
        __builtin_amdgcn_global_load_lds(AS1(g), AS3(&AB[c0 * 8]), 16, 0, 0);
    }
    __syncthreads();

    const int ln_ = lane & 15, quad = lane >> 4;
    const int m0 = (w >> 1) * 64, n0 = (w & 1) * 64;
    floatx4 acc[4][4] = {};
    for (int kk = 0; kk < 8; ++kk) {
        int ckb = kk * 4 + quad;
        short8 aq[4], bq[4];
#pragma unroll
        for (int t = 0; t < 4; ++t) {
            int r = m0 + t * 16 + ln_;
            aq[t] = *(const short8*)&AB[((r * 32) + (ckb ^ (r & 31))) * 8];
        }
#pragma unroll
        for (int t = 0; t < 4; ++t) {
            int r = n0 + t * 16 + ln_;
            bq[t] = *(const short8*)&AB[(4096 + (r * 32) + (ckb ^ (r & 31))) * 8];
        }
#pragma unroll
        for (int mt = 0; mt < 4; ++mt)
#pragma unroll
            for (int nt = 0; nt < 4; ++nt)
                acc[mt][nt] = __builtin_amdgcn_mfma_f32_16x16x32_bf16(aq[mt], bq[nt], acc[mt][nt], 0, 0, 0);
    }

    const int c0col = (part ? (8 + h) : h) * 16;
#pragma unroll
    for (int mt = 0; mt < 4; ++mt) {
#pragma unroll
        for (int nt = 0; nt < 4; ++nt) {
            int j = (jd0 + n0 + nt * 16) >> 4;
            int ib = i0 + m0 + mt * 16 + quad * 4;
#pragma unroll
            for (int r = 0; r < 4; ++r) {
                size_t off = (((size_t)b * 256 + (ib + r)) * 256 + j) * 256 + c0col + ln_;
                VaP[off] = f2bf(acc[mt][nt][r]);
            }
        }
    }
}

// ---------------------------------------------------------------------------
// K4: out[m][w] = sum_c VaP[m][c] * WOt[w][c] + bO[w]. Same tile structure.
// ---------------------------------------------------------------------------
__global__ __launch_bounds__(256) void k4_proj(const short* __restrict__ VaP,
                                               const short* __restrict__ WOt,
                                               const float* __restrict__ bO,
                                               float* __restrict__ out) {
    __shared__ short AB[8192 * 8];
    const int tid = threadIdx.x, lane = tid & 63, w = tid >> 6;
    const size_t m0g = (size_t)blockIdx.x * 128;
    const short* Abase = VaP + m0g * 256;

    for (int it = 0; it < 32; ++it) {
        int c0 = (w * 32 + it) * 64;
        int lc = c0 + lane;
        const short* g;
        if (c0 < 4096) {
            int r = lc >> 5;
            int ck = (lc & 31) ^ (r & 31);
            g = Abase + r * 256 + ck * 8;
        } else {
            int lb = lc - 4096;
            int r = lb >> 5;
            int ck = (lb & 31) ^ (r & 31);
            g = WOt + r * 256 + ck * 8;
        }
        __builtin_amdgcn_global_load_lds(AS1(g), AS3(&AB[c0 * 8]), 16, 0, 0);
    }
    __syncthreads();

    const int ln_ = lane & 15, quad = lane >> 4;
    const int m0 = (w >> 1) * 64, n0 = (w & 1) * 64;
    floatx4 acc[4][4] = {};
    for (int kk = 0; kk < 8; ++kk) {
        int ckb = kk * 4 + quad;
        short8 aq[4], bq[4];
#pragma unroll
        for (int t = 0; t < 4; ++t) {
            int r = m0 + t * 16 + ln_;
            aq[t] = *(const short8*)&AB[((r * 32) + (ckb ^ (r & 31))) * 8];
        }
#pragma unroll
        for (int t = 0; t < 4; ++t) {
            int r = n0 + t * 16 + ln_;
            bq[t] = *(const short8*)&AB[(4096 + (r * 32) + (ckb ^ (r & 31))) * 8];
        }
#pragma unroll
        for (int mt = 0; mt < 4; ++mt)
#pragma unroll
            for (int nt = 0; nt < 4; ++nt)
                acc[mt][nt] = __builtin_amdgcn_mfma_f32_16x16x32_bf16(aq[mt], bq[nt], acc[mt][nt], 0, 0, 0);
    }

#pragma unroll
    for (int nt = 0; nt < 4; ++nt) {
        int ww = n0 + nt * 16 + ln_;
        float bo = bO[ww];
#pragma unroll
        for (int mt = 0; mt < 4; ++mt) {
            size_t mb = m0g + m0 + mt * 16 + quad * 4;
#pragma unroll
            for (int r = 0; r < 4; ++r)
                out[(mb + r) * 128 + ww] = acc[mt][nt][r] + bo;
        }
    }
}

// ---------------------------------------------------------------------------
extern "C" void kernel_launch(void* const* d_in, const int* in_sizes, int n_in,
                              void* d_out, int out_size, void* d_ws, size_t ws_size,
                              hipStream_t stream) {
    (void)in_sizes; (void)n_in; (void)out_size; (void)ws_size;
    const float* e    = (const float*)d_in[0];
    const float* mask = (const float*)d_in[1];
    const float* ln_g = (const float*)d_in[2];
    const float* ln_b = (const float*)d_in[3];
    const float* W_V  = (const float*)d_in[4];
    const float* b_V  = (const float*)d_in[5];
    const float* W_E  = (const float*)d_in[6];
    const float* b_E  = (const float*)d_in[7];
    const float* W_O  = (const float*)d_in[8];
    const float* b_O  = (const float*)d_in[9];
    float* out = (float*)d_out;

    char* ws = (char*)d_ws;
    short* VinT  = (short*)(ws + 0);          //  33,554,432 B
    short* VoutT = (short*)(ws + 33554432);   //  33,554,432 B
    float* Ef    = (float*)(ws + 67108864);   //   8,388,608 B
    short* Ain   = (short*)(ws + 75497472);   //   2,097,152 B
    short* AoutT = (short*)(ws + 77594624);   //   2,097,152 B
    short* VaP   = (short*)(ws + 79691776);   //  67,108,864 B
    short* Wcat  = (short*)(ws + 146800640);  //      69,632 B
    short* WOt   = (short*)(ws + 146870272);  //      65,536 B  (total ~140.1 MB)

    k0_prep<<<400, 128, 0, stream>>>(W_V, W_E, W_O, Wcat, WOt);
    k1_ln_proj<<<2048, 256, 0, stream>>>(e, ln_g, ln_b, b_V, b_E, Wcat, VinT, VoutT, Ef);
    k2_softmax<<<512, 256, 0, stream>>>(Ef, mask, Ain, AoutT);
    k3_einsum<<<dim3(32, 2, 32), 256, 0, stream>>>(Ain, AoutT, VinT, VoutT, VaP);
    k4_proj<<<1024, 256, 0, stream>>>(VaP, WOt, b_O, out);
}